// Round 18
// baseline (7746.004 us; speedup 1.0000x reference)
//
#include <hip/hip_runtime.h>
#include <hip/hip_fp16.h>

#define T_STEPS 2048
#define B_SZ 128
#define I_SZ 10
#define H_SZ 512

#define NGRP 8            // batch groups (16 rows each)
#define GWG 8             // wgs per group
#define NWG (NGRP * GWG)  // 64 workgroups
#define BSLICE 16         // batch rows per group
#define WCOL 64           // hidden cols per wg
#define NTHR 512

typedef _Float16 f16x8 __attribute__((ext_vector_type(8)));
typedef float f32x4 __attribute__((ext_vector_type(4)));
typedef float f32x2 __attribute__((ext_vector_type(2)));
typedef unsigned u32x4 __attribute__((ext_vector_type(4)));
typedef unsigned u32x2 __attribute__((ext_vector_type(2)));
typedef unsigned long long u64t;

// ws layout: [0, 512KB) tagged h double-buffer [2][NGRP][BSLICE][H/2] u64
//            [512KB, 512KB+1KB) sentinel tags u32[2][NGRP][16]
// u64 granule = (tag << 32) | 2xfp16. Everything cleared each launch
// (stale tags / 0xAA poison would satisfy tag checks).
__global__ void clear_ws_kernel(u64t* p) {
    const int i = blockIdx.x * 256 + threadIdx.x;   // 64 blocks x 256
    #pragma unroll
    for (int k = 0; k < 4; ++k)
        __hip_atomic_store(p + i + k * 16384, 0ull,
                           __ATOMIC_RELAXED, __HIP_MEMORY_SCOPE_AGENT);
    if (blockIdx.x == 0) {
        unsigned* s = (unsigned*)(p + 65536);       // sentinel region, 256 u32
        __hip_atomic_store(&s[threadIdx.x], 0u,
                           __ATOMIC_RELAXED, __HIP_MEMORY_SCOPE_AGENT);
    }
}

// Persistent LSTM = R13 (best proven: 6.49ms) + compact sentinel line.
//
//   8 batch-groups x 8 wgs; wg owns 64 hidden cols (all 4 gates, full K) of
//   its group's 16 batch rows; 8 waves, wf[2][16] fp16 register-resident
//   (128 VGPR, 2 waves/SIMD).
//
//   publish: each thread fire-and-forgets ONE tagged u64 {t+2 | 2xfp16}
//   (relaxed agent = sc0 sc1, coherent at LLC). No drain, no barrier.
//   Thread 511 additionally fire-and-forgets its tag into the group's
//   SENTINEL LINE (u32[16] per (parity,group) — ONE cache line).
//   consume: wave0 spins on the sentinel line (1 line/retry vs R13's 8),
//   then spinB -> ONE coalesced sweep (1KB contiguous per instruction)
//   validating per-granule tags; stale granules re-read exec-masked.
//   Sentinels are ADVISORY ONLY — correctness rests on granule tags.
//
// Double-buffer safety (R9/R10/R13 proof): publish at end of step s writes
// tag s+2 into buf[(s+1)&1]; overwriting buf[p] again requires every wg to
// have passed staging(t) of buf[p], enforced by the granule tag chain.
// LDS WAR: B2(t) separates all h_stage reads(t) from sweep-writes(t+1).
__global__ __launch_bounds__(NTHR, 2) void lstm_persistent(
    const float* __restrict__ x,     // [T,B,I]
    const float* __restrict__ hx,    // [B,H]
    const float* __restrict__ cx,    // [B,H]
    const float* __restrict__ W_ih,  // [4H,I]
    const float* __restrict__ W_hh,  // [4H,H]
    const float* __restrict__ b_ih,  // [4H]
    const float* __restrict__ b_hh,  // [4H]
    float* __restrict__ out,         // [3*B*H] = h, h, c
    u64t* hbuf,                      // [2][NGRP][BSLICE][H/2] tagged
    unsigned* sent)                  // [2][NGRP][16] sentinel tags
{
    __shared__ _Float16 h_stage[BSLICE][520];   // row stride 1040B
    __shared__ float lds_g[4 * WCOL][17];       // [gate*64+col][row], padded

    const int wg   = blockIdx.x;
    const int g    = wg >> 3;          // batch group 0..7
    const int wgin = wg & 7;           // wg within group 0..7
    const int tid  = threadIdx.x;
    const int wid  = tid >> 6;         // wave 0..7
    const int lane = tid & 63;
    const int fr_col = lane & 15;
    const int fr_kg  = lane >> 4;      // 0..3

    // ---- this wave's two gate-column fragments (wg covers 256 gate-cols)
    int gcL[2], wr[2];
    #pragma unroll
    for (int f = 0; f < 2; ++f) {
        gcL[f] = wid * 32 + f * 16 + fr_col;              // 0..255
        wr[f]  = (gcL[f] >> 6) * H_SZ + wgin * WCOL + (gcL[f] & 63);
    }

    // ---- W_hh B-fragments: 2 frags x 16 K-chunks, fp16 register-resident
    f16x8 wf[2][16];
    #pragma unroll
    for (int f = 0; f < 2; ++f)
        #pragma unroll
        for (int c = 0; c < 16; ++c) {
            const float* p = W_hh + (size_t)wr[f] * H_SZ + c * 32 + fr_kg * 8;
            f16x8 w;
            #pragma unroll
            for (int e = 0; e < 8; ++e) w[e] = (_Float16)p[e];
            wf[f][c] = w;
        }

    // ---- W_ih rows + combined bias
    float wih[2][I_SZ], bias[2];
    #pragma unroll
    for (int f = 0; f < 2; ++f) {
        #pragma unroll
        for (int i = 0; i < I_SZ; ++i) wih[f][i] = W_ih[wr[f] * I_SZ + i];
        bias[f] = b_ih[wr[f]] + b_hh[wr[f]];
    }

    // ---- owned cells: 2 adjacent per thread (16 rows x 64 cols per wg)
    const int orow  = tid >> 5;                    // 0..15
    const int ocol  = wgin * WCOL + 2 * (tid & 31);
    const int gbrow = g * BSLICE + orow;
    const size_t my_q = (size_t)orow * 256 + (ocol >> 1);   // u64 idx in slice

    float c0 = cx[gbrow * H_SZ + ocol];
    float c1 = cx[gbrow * H_SZ + ocol + 1];
    float h0 = hx[gbrow * H_SZ + ocol];
    float h1 = hx[gbrow * H_SZ + ocol + 1];

    // ---- staging geometry (coalesced): piece j of this lane
    int   st_row[4], st_p[4];
    bool  st_own[4];
    #pragma unroll
    for (int j = 0; j < 4; ++j) {
        const int q = wid * 512 + j * 128 + lane * 2;
        st_row[j] = q >> 8;
        st_p[j]   = q & 255;
        st_own[j] = ((st_p[j] >> 5) == wgin);
    }

    // ---- publish h(0) with tag 1 into buffer 0 + own-tile LDS write
    {
        u64t* hb0 = hbuf + (size_t)g * (BSLICE * 256);
        union { _Float16 hp[2]; unsigned u; } pk;
        pk.hp[0] = (_Float16)h0; pk.hp[1] = (_Float16)h1;
        __hip_atomic_store(hb0 + my_q, ((u64t)1u << 32) | pk.u,
                           __ATOMIC_RELAXED, __HIP_MEMORY_SCOPE_AGENT);
        *(unsigned*)&h_stage[orow][ocol] = pk.u;
        if (tid == NTHR - 1)
            __hip_atomic_store(&sent[g * 16 + wgin], 1u,
                               __ATOMIC_RELAXED, __HIP_MEMORY_SCOPE_AGENT);
    }

    #pragma unroll 1
    for (int t = 0; t < T_STEPS; ++t) {
        // -- x_t @ W_ih^T + bias (h-independent; overlaps sentinel landing)
        f32x4 acc[2];
        #pragma unroll
        for (int r = 0; r < 4; ++r) {
            const int grow = g * BSLICE + fr_kg * 4 + r;
            const f32x2* xp = (const f32x2*)(x + ((size_t)t * B_SZ + grow) * I_SZ);
            const f32x2 a0 = xp[0], a1 = xp[1], a2 = xp[2], a3 = xp[3], a4 = xp[4];
            #pragma unroll
            for (int f = 0; f < 2; ++f) {
                float s = bias[f];
                s += a0.x*wih[f][0] + a0.y*wih[f][1] + a1.x*wih[f][2] + a1.y*wih[f][3]
                   + a2.x*wih[f][4] + a2.y*wih[f][5] + a3.x*wih[f][6] + a3.y*wih[f][7]
                   + a4.x*wih[f][8] + a4.y*wih[f][9];
                acc[f][r] = s;
            }
        }

        const u64t* hb = hbuf + ((size_t)(t & 1) * NGRP + g) * (BSLICE * 256);
        const unsigned tgt = (unsigned)(t + 1);

        // -- sentinel spin: wave0 only, ONE 64B line per retry
        if (wid == 0) {
            const unsigned* sp = sent + (t & 1) * 128 + g * 16 + (lane & 7);
            for (;;) {
                unsigned sv = __hip_atomic_load(sp, __ATOMIC_RELAXED,
                                                __HIP_MEMORY_SCOPE_AGENT);
                if (__all(sv >= tgt)) break;
                __builtin_amdgcn_s_sleep(1);
            }
        }
        __syncthreads();   // spinB

        // -- ONE coalesced tagged sweep (validate granule tags; stale
        //    granules re-read exec-masked; own pieces skip — already in LDS)
        {
            const char* sp = (const char*)hb + wid * 4096 + lane * 16;
            u32x4 q0, q1, q2, q3;
            bool done = false;
            for (;;) {
                if (!done) {
                    asm volatile(
                        "global_load_dwordx4 %0, %4, off sc0 sc1\n\t"
                        "global_load_dwordx4 %1, %4, off offset:1024 sc0 sc1\n\t"
                        "global_load_dwordx4 %2, %4, off offset:2048 sc0 sc1\n\t"
                        "global_load_dwordx4 %3, %4, off offset:3072 sc0 sc1\n\t"
                        "s_waitcnt vmcnt(0)"
                        : "=&v"(q0), "=&v"(q1), "=&v"(q2), "=&v"(q3)
                        : "v"(sp) : "memory");
                    done = (st_own[0] || (q0.y >= tgt && q0.w >= tgt)) &&
                           (st_own[1] || (q1.y >= tgt && q1.w >= tgt)) &&
                           (st_own[2] || (q2.y >= tgt && q2.w >= tgt)) &&
                           (st_own[3] || (q3.y >= tgt && q3.w >= tgt));
                }
                if (__all(done)) break;
                __builtin_amdgcn_s_sleep(1);
            }
            if (!st_own[0]) *(u32x2*)&h_stage[st_row[0]][st_p[0] * 2] = (u32x2){q0.x, q0.z};
            if (!st_own[1]) *(u32x2*)&h_stage[st_row[1]][st_p[1] * 2] = (u32x2){q1.x, q1.z};
            if (!st_own[2]) *(u32x2*)&h_stage[st_row[2]][st_p[2] * 2] = (u32x2){q2.x, q2.z};
            if (!st_own[3]) *(u32x2*)&h_stage[st_row[3]][st_p[3] * 2] = (u32x2){q3.x, q3.z};
        }
        __syncthreads();   // B1: staging visible

        // -- 16 K-chunks: ds_read A-frag, 2 MFMAs each
        #pragma unroll
        for (int c = 0; c < 16; ++c) {
            const f16x8 a = *(const f16x8*)&h_stage[fr_col][c * 32 + fr_kg * 8];
            acc[0] = __builtin_amdgcn_mfma_f32_16x16x32_f16(a, wf[0][c], acc[0], 0, 0, 0);
            acc[1] = __builtin_amdgcn_mfma_f32_16x16x32_f16(a, wf[1][c], acc[1], 0, 0, 0);
        }

        // -- gate pre-activations -> LDS
        #pragma unroll
        for (int f = 0; f < 2; ++f)
            #pragma unroll
            for (int r = 0; r < 4; ++r)
                lds_g[gcL[f]][fr_kg * 4 + r] = acc[f][r];
        __syncthreads();   // B2: gates visible; fences all h_stage reads

        // -- c/h update; fire-and-forget tagged publish + own-tile shortcut
        {
            const int cl = 2 * (tid & 31);
            const float i0 = lds_g[0 * WCOL + cl][orow],     f0 = lds_g[1 * WCOL + cl][orow];
            const float g0 = lds_g[2 * WCOL + cl][orow],     o0 = lds_g[3 * WCOL + cl][orow];
            const float i1 = lds_g[0 * WCOL + cl + 1][orow], f1 = lds_g[1 * WCOL + cl + 1][orow];
            const float g1 = lds_g[2 * WCOL + cl + 1][orow], o1 = lds_g[3 * WCOL + cl + 1][orow];

            const float ig0 = 1.f / (1.f + __expf(-i0));
            const float fg0 = 1.f / (1.f + __expf(-f0));
            const float eg0 = __expf(-2.f * g0);
            const float tg0 = (1.f - eg0) / (1.f + eg0);
            const float og0 = 1.f / (1.f + __expf(-o0));
            const float ig1 = 1.f / (1.f + __expf(-i1));
            const float fg1 = 1.f / (1.f + __expf(-f1));
            const float eg1 = __expf(-2.f * g1);
            const float tg1 = (1.f - eg1) / (1.f + eg1);
            const float og1 = 1.f / (1.f + __expf(-o1));

            c0 = fg0 * c0 + ig0 * tg0;
            c1 = fg1 * c1 + ig1 * tg1;
            const float e0 = __expf(-2.f * c0), e1 = __expf(-2.f * c1);
            h0 = og0 * (1.f - e0) / (1.f + e0);
            h1 = og1 * (1.f - e1) / (1.f + e1);

            if (t < T_STEPS - 1) {
                u64t* hbn = hbuf + ((size_t)((t + 1) & 1) * NGRP + g) * (BSLICE * 256);
                union { _Float16 hp[2]; unsigned u; } pk;
                pk.hp[0] = (_Float16)h0; pk.hp[1] = (_Float16)h1;
                __hip_atomic_store(hbn + my_q,
                                   ((u64t)(unsigned)(t + 2) << 32) | pk.u,
                                   __ATOMIC_RELAXED, __HIP_MEMORY_SCOPE_AGENT);
                *(unsigned*)&h_stage[orow][ocol] = pk.u;   // own-tile shortcut
                if (tid == NTHR - 1)
                    __hip_atomic_store(&sent[((t + 1) & 1) * 128 + g * 16 + wgin],
                                       (unsigned)(t + 2),
                                       __ATOMIC_RELAXED, __HIP_MEMORY_SCOPE_AGENT);
            }
        }
    }

    // ---- outputs: (h, h, c), each [B,H] f32
    out[gbrow * H_SZ + ocol]                       = h0;
    out[gbrow * H_SZ + ocol + 1]                   = h1;
    out[B_SZ * H_SZ + gbrow * H_SZ + ocol]         = h0;
    out[B_SZ * H_SZ + gbrow * H_SZ + ocol + 1]     = h1;
    out[2 * B_SZ * H_SZ + gbrow * H_SZ + ocol]     = c0;
    out[2 * B_SZ * H_SZ + gbrow * H_SZ + ocol + 1] = c1;
}

extern "C" void kernel_launch(void* const* d_in, const int* in_sizes, int n_in,
                              void* d_out, int out_size, void* d_ws, size_t ws_size,
                              hipStream_t stream) {
    const float* x    = (const float*)d_in[0];
    const float* hx   = (const float*)d_in[1];
    const float* cx   = (const float*)d_in[2];
    const float* W_ih = (const float*)d_in[3];
    const float* W_hh = (const float*)d_in[4];
    const float* b_ih = (const float*)d_in[5];
    const float* b_hh = (const float*)d_in[6];
    float* out = (float*)d_out;

    u64t* hbuf = (u64t*)d_ws;
    unsigned* sent = (unsigned*)((char*)d_ws + 512 * 1024);

    clear_ws_kernel<<<64, 256, 0, stream>>>(hbuf);
    lstm_persistent<<<NWG, NTHR, 0, stream>>>(x, hx, cx, W_ih, W_hh, b_ih, b_hh,
                                              out, hbuf, sent);
}

// Round 19
// 6539.264 us; speedup vs baseline: 1.1845x; 1.1845x over previous
//
#include <hip/hip_runtime.h>
#include <hip/hip_fp16.h>

#define T_STEPS 2048
#define B_SZ 128
#define I_SZ 10
#define H_SZ 512

#define NGRP 8            // batch groups (16 rows each)
#define GWG 8             // wgs per group
#define NWG (NGRP * GWG)  // 64 workgroups
#define BSLICE 16         // batch rows per group
#define WCOL 64           // hidden cols per wg
#define NTHR 512

typedef _Float16 f16x8 __attribute__((ext_vector_type(8)));
typedef float f32x4 __attribute__((ext_vector_type(4)));
typedef float f32x2 __attribute__((ext_vector_type(2)));
typedef unsigned u32x4 __attribute__((ext_vector_type(4)));
typedef unsigned u32x2 __attribute__((ext_vector_type(2)));
typedef unsigned long long u64t;

// Tagged h buffers: [2][NGRP][BSLICE][H/2] u64, u64 = (tag << 32) | 2xfp16.
// MUST be zeroed before every persistent launch (stale tags / 0xAA poison
// would satisfy the tag check).
__global__ void clear_hbuf_kernel(u64t* p) {
    const int i = blockIdx.x * 256 + threadIdx.x;   // 16384 threads
    #pragma unroll
    for (int k = 0; k < 4; ++k)
        __hip_atomic_store(p + i + k * 16384, 0ull,
                           __ATOMIC_RELAXED, __HIP_MEMORY_SCOPE_AGENT);
}

// Persistent LSTM = R13 (6.49ms, best proven) + TWO-PHASE SWEEP PIPELINE.
//
//   8 batch-groups x 8 wgs; wg owns 64 hidden cols (all 4 gates, full K) of
//   its group's 16 batch rows; 8 waves; wf[2][16] fp16 register-resident.
//
//   publish: each thread fire-and-forgets ONE tagged u64 {t+2 | 2xfp16}
//   (relaxed agent = sc0 sc1, coherent at LLC). No drain, no flag array.
//   consume: wave0 spins on 8 sentinel granules (spread across 8 lines,
//   2KB apart — the R18 compact-line variant REGRESSED) -> spinB ->
//   TWO-PHASE sweep: issue all 4x1KB loads, vmcnt(2) -> validate+stage
//   colpair half 0 (K-chunks 0..7) -> B1a -> MFMA chunks 0..7 WHILE half 1
//   is still in flight -> vmcnt(0) -> validate+stage half 1 -> B1b ->
//   MFMA chunks 8..15. Per-granule tags validated on every piece; stale
//   granules re-read exec-masked (correctness rests on tags only).
//
//   Piece map: wave wid stages rows {2wid, 2wid+1}; half h covers colpairs
//   [h*128, h*128+128) (1KB contiguous per instruction, lane*16B). Offsets
//   from sp = base + wid*4096 + lane*16: h0 = {0, 2048}, h1 = {1024, 3072}.
//   vmcnt retires in issue order, so vmcnt(2) == h0 pieces complete.
//
// Double-buffer safety (R9/R10/R13 proof): publish at end of step s writes
// tag s+2 into buf[(s+1)&1]; overwriting buf[p] again requires every wg to
// have passed staging(t) of buf[p], enforced by the granule tag chain.
// LDS WAR: chunk 0..7 reads precede B1b(t); spinB(t+1) (a barrier after
// B1b(t) for every wave) precedes any h0(t+1) staging write. Half-1 writes
// (post-B1a) touch cols 256.. only, disjoint from chunk 0..7 reads.
__global__ __launch_bounds__(NTHR, 2) void lstm_persistent(
    const float* __restrict__ x,     // [T,B,I]
    const float* __restrict__ hx,    // [B,H]
    const float* __restrict__ cx,    // [B,H]
    const float* __restrict__ W_ih,  // [4H,I]
    const float* __restrict__ W_hh,  // [4H,H]
    const float* __restrict__ b_ih,  // [4H]
    const float* __restrict__ b_hh,  // [4H]
    float* __restrict__ out,         // [3*B*H] = h, h, c
    u64t* hbuf)                      // [2][NGRP][BSLICE][H/2] tagged
{
    __shared__ _Float16 h_stage[BSLICE][520];   // row stride 1040B
    __shared__ float lds_g[4 * WCOL][17];       // [gate*64+col][row], padded

    const int wg   = blockIdx.x;
    const int g    = wg >> 3;          // batch group 0..7
    const int wgin = wg & 7;           // wg within group 0..7
    const int tid  = threadIdx.x;
    const int wid  = tid >> 6;         // wave 0..7
    const int lane = tid & 63;
    const int fr_col = lane & 15;
    const int fr_kg  = lane >> 4;      // 0..3

    // ---- this wave's two gate-column fragments (wg covers 256 gate-cols)
    int gcL[2], wr[2];
    #pragma unroll
    for (int f = 0; f < 2; ++f) {
        gcL[f] = wid * 32 + f * 16 + fr_col;              // 0..255
        wr[f]  = (gcL[f] >> 6) * H_SZ + wgin * WCOL + (gcL[f] & 63);
    }

    // ---- W_hh B-fragments: 2 frags x 16 K-chunks, fp16 register-resident
    f16x8 wf[2][16];
    #pragma unroll
    for (int f = 0; f < 2; ++f)
        #pragma unroll
        for (int c = 0; c < 16; ++c) {
            const float* p = W_hh + (size_t)wr[f] * H_SZ + c * 32 + fr_kg * 8;
            f16x8 w;
            #pragma unroll
            for (int e = 0; e < 8; ++e) w[e] = (_Float16)p[e];
            wf[f][c] = w;
        }

    // ---- W_ih rows + combined bias
    float wih[2][I_SZ], bias[2];
    #pragma unroll
    for (int f = 0; f < 2; ++f) {
        #pragma unroll
        for (int i = 0; i < I_SZ; ++i) wih[f][i] = W_ih[wr[f] * I_SZ + i];
        bias[f] = b_ih[wr[f]] + b_hh[wr[f]];
    }

    // ---- owned cells: 2 adjacent per thread (16 rows x 64 cols per wg)
    const int orow  = tid >> 5;                    // 0..15
    const int ocol  = wgin * WCOL + 2 * (tid & 31);
    const int gbrow = g * BSLICE + orow;
    const size_t my_q = (size_t)orow * 256 + (ocol >> 1);   // u64 idx in slice

    float c0 = cx[gbrow * H_SZ + ocol];
    float c1 = cx[gbrow * H_SZ + ocol + 1];
    float h0 = hx[gbrow * H_SZ + ocol];
    float h1 = hx[gbrow * H_SZ + ocol + 1];

    // ---- staging ownership: half h covers colpairs [h*128, h*128+128);
    //      this lane's colpairs in half h are {h*128+lane*2, +1}.
    const bool own0 = ((lane >> 4) == wgin);          // wgin 0..3 only
    const bool own1 = ((lane >> 4) + 4 == wgin);      // wgin 4..7 only

    // ---- sentinel for producer wg p = granule (row 15, last colpair of p)
    //      (8 sentinels on 8 DISTINCT lines — R18's shared line regressed)
    const int sent_idx = 15 * 256 + (lane & 7) * 32 + 31;

    // ---- publish h(0) with tag 1 into buffer 0 + own-tile LDS write
    {
        u64t* hb0 = hbuf + (size_t)g * (BSLICE * 256);
        union { _Float16 hp[2]; unsigned u; } pk;
        pk.hp[0] = (_Float16)h0; pk.hp[1] = (_Float16)h1;
        __hip_atomic_store(hb0 + my_q, ((u64t)1u << 32) | pk.u,
                           __ATOMIC_RELAXED, __HIP_MEMORY_SCOPE_AGENT);
        *(unsigned*)&h_stage[orow][ocol] = pk.u;
    }

    #pragma unroll 1
    for (int t = 0; t < T_STEPS; ++t) {
        // -- x_t @ W_ih^T + bias (h-independent; overlaps sentinel landing)
        f32x4 acc[2];
        #pragma unroll
        for (int r = 0; r < 4; ++r) {
            const int grow = g * BSLICE + fr_kg * 4 + r;
            const f32x2* xp = (const f32x2*)(x + ((size_t)t * B_SZ + grow) * I_SZ);
            const f32x2 a0 = xp[0], a1 = xp[1], a2 = xp[2], a3 = xp[3], a4 = xp[4];
            #pragma unroll
            for (int f = 0; f < 2; ++f) {
                float s = bias[f];
                s += a0.x*wih[f][0] + a0.y*wih[f][1] + a1.x*wih[f][2] + a1.y*wih[f][3]
                   + a2.x*wih[f][4] + a2.y*wih[f][5] + a3.x*wih[f][6] + a3.y*wih[f][7]
                   + a4.x*wih[f][8] + a4.y*wih[f][9];
                acc[f][r] = s;
            }
        }

        const u64t* hb = hbuf + ((size_t)(t & 1) * NGRP + g) * (BSLICE * 256);
        const unsigned tgt = (unsigned)(t + 1);

        // -- sentinel spin: wave0 only, 8 granules on 8 distinct lines
        if (wid == 0) {
            const u64t* sp = hb + sent_idx;
            for (;;) {
                u64t sv = __hip_atomic_load(sp, __ATOMIC_RELAXED,
                                            __HIP_MEMORY_SCOPE_AGENT);
                if (__all((unsigned)(sv >> 32) >= tgt)) break;
                __builtin_amdgcn_s_sleep(1);
            }
        }
        __syncthreads();   // spinB: sentinels fresh; fences h_stage WAR

        // -- TWO-PHASE sweep: issue all 4 loads; overlap half 1 with MFMA 0..7
        const char* sp = (const char*)hb + wid * 4096 + lane * 16;
        u32x4 q0, q1, q2, q3;
        asm volatile(
            "global_load_dwordx4 %0, %4, off sc0 sc1\n\t"              // h0 row 2w
            "global_load_dwordx4 %1, %4, off offset:2048 sc0 sc1\n\t"  // h0 row 2w+1
            "global_load_dwordx4 %2, %4, off offset:1024 sc0 sc1\n\t"  // h1 row 2w
            "global_load_dwordx4 %3, %4, off offset:3072 sc0 sc1\n\t"  // h1 row 2w+1
            "s_waitcnt vmcnt(2)"
            : "=&v"(q0), "=&v"(q1), "=&v"(q2), "=&v"(q3)
            : "v"(sp) : "memory");
        __builtin_amdgcn_sched_barrier(0);

        // validate + stage half 0 (colpairs 0..127 -> cols 0..255)
        {
            bool ok = own0 || (q0.y >= tgt && q0.w >= tgt &&
                               q1.y >= tgt && q1.w >= tgt);
            for (;;) {
                if (__all(ok)) break;
                __builtin_amdgcn_s_sleep(1);
                if (!ok) {
                    asm volatile(
                        "global_load_dwordx4 %0, %2, off sc0 sc1\n\t"
                        "global_load_dwordx4 %1, %2, off offset:2048 sc0 sc1\n\t"
                        "s_waitcnt vmcnt(0)"
                        : "+v"(q0), "+v"(q1) : "v"(sp) : "memory");
                    ok = (q0.y >= tgt && q0.w >= tgt &&
                          q1.y >= tgt && q1.w >= tgt);
                }
            }
            if (!own0) {
                *(u32x2*)&h_stage[2 * wid][lane * 4]     = (u32x2){q0.x, q0.z};
                *(u32x2*)&h_stage[2 * wid + 1][lane * 4] = (u32x2){q1.x, q1.z};
            }
        }
        __syncthreads();   // B1a: half-0 staging visible

        // -- MFMA K-chunks 0..7 (cols 0..255) while half 1 is in flight
        #pragma unroll
        for (int c = 0; c < 8; ++c) {
            const f16x8 a = *(const f16x8*)&h_stage[fr_col][c * 32 + fr_kg * 8];
            acc[0] = __builtin_amdgcn_mfma_f32_16x16x32_f16(a, wf[0][c], acc[0], 0, 0, 0);
            acc[1] = __builtin_amdgcn_mfma_f32_16x16x32_f16(a, wf[1][c], acc[1], 0, 0, 0);
        }

        // -- half 1 arrival (long done by now), validate + stage
        asm volatile("s_waitcnt vmcnt(0)" : "+v"(q2), "+v"(q3) :: "memory");
        __builtin_amdgcn_sched_barrier(0);
        {
            bool ok = own1 || (q2.y >= tgt && q2.w >= tgt &&
                               q3.y >= tgt && q3.w >= tgt);
            for (;;) {
                if (__all(ok)) break;
                __builtin_amdgcn_s_sleep(1);
                if (!ok) {
                    asm volatile(
                        "global_load_dwordx4 %0, %2, off offset:1024 sc0 sc1\n\t"
                        "global_load_dwordx4 %1, %2, off offset:3072 sc0 sc1\n\t"
                        "s_waitcnt vmcnt(0)"
                        : "+v"(q2), "+v"(q3) : "v"(sp) : "memory");
                    ok = (q2.y >= tgt && q2.w >= tgt &&
                          q3.y >= tgt && q3.w >= tgt);
                }
            }
            if (!own1) {
                *(u32x2*)&h_stage[2 * wid][256 + lane * 4]     = (u32x2){q2.x, q2.z};
                *(u32x2*)&h_stage[2 * wid + 1][256 + lane * 4] = (u32x2){q3.x, q3.z};
            }
        }
        __syncthreads();   // B1b: half-1 staging visible

        // -- MFMA K-chunks 8..15 (cols 256..511)
        #pragma unroll
        for (int c = 8; c < 16; ++c) {
            const f16x8 a = *(const f16x8*)&h_stage[fr_col][c * 32 + fr_kg * 8];
            acc[0] = __builtin_amdgcn_mfma_f32_16x16x32_f16(a, wf[0][c], acc[0], 0, 0, 0);
            acc[1] = __builtin_amdgcn_mfma_f32_16x16x32_f16(a, wf[1][c], acc[1], 0, 0, 0);
        }

        // -- gate pre-activations -> LDS
        #pragma unroll
        for (int f = 0; f < 2; ++f)
            #pragma unroll
            for (int r = 0; r < 4; ++r)
                lds_g[gcL[f]][fr_kg * 4 + r] = acc[f][r];
        __syncthreads();   // B2: gates visible; fences all h_stage reads

        // -- c/h update; fire-and-forget tagged publish + own-tile shortcut
        {
            const int cl = 2 * (tid & 31);
            const float i0 = lds_g[0 * WCOL + cl][orow],     f0 = lds_g[1 * WCOL + cl][orow];
            const float g0 = lds_g[2 * WCOL + cl][orow],     o0 = lds_g[3 * WCOL + cl][orow];
            const float i1 = lds_g[0 * WCOL + cl + 1][orow], f1 = lds_g[1 * WCOL + cl + 1][orow];
            const float g1 = lds_g[2 * WCOL + cl + 1][orow], o1 = lds_g[3 * WCOL + cl + 1][orow];

            const float ig0 = 1.f / (1.f + __expf(-i0));
            const float fg0 = 1.f / (1.f + __expf(-f0));
            const float eg0 = __expf(-2.f * g0);
            const float tg0 = (1.f - eg0) / (1.f + eg0);
            const float og0 = 1.f / (1.f + __expf(-o0));
            const float ig1 = 1.f / (1.f + __expf(-i1));
            const float fg1 = 1.f / (1.f + __expf(-f1));
            const float eg1 = __expf(-2.f * g1);
            const float tg1 = (1.f - eg1) / (1.f + eg1);
            const float og1 = 1.f / (1.f + __expf(-o1));

            c0 = fg0 * c0 + ig0 * tg0;
            c1 = fg1 * c1 + ig1 * tg1;
            const float e0 = __expf(-2.f * c0), e1 = __expf(-2.f * c1);
            h0 = og0 * (1.f - e0) / (1.f + e0);
            h1 = og1 * (1.f - e1) / (1.f + e1);

            if (t < T_STEPS - 1) {
                u64t* hbn = hbuf + ((size_t)((t + 1) & 1) * NGRP + g) * (BSLICE * 256);
                union { _Float16 hp[2]; unsigned u; } pk;
                pk.hp[0] = (_Float16)h0; pk.hp[1] = (_Float16)h1;
                __hip_atomic_store(hbn + my_q,
                                   ((u64t)(unsigned)(t + 2) << 32) | pk.u,
                                   __ATOMIC_RELAXED, __HIP_MEMORY_SCOPE_AGENT);
                *(unsigned*)&h_stage[orow][ocol] = pk.u;   // own-tile shortcut
            }
        }
    }

    // ---- outputs: (h, h, c), each [B,H] f32
    out[gbrow * H_SZ + ocol]                       = h0;
    out[gbrow * H_SZ + ocol + 1]                   = h1;
    out[B_SZ * H_SZ + gbrow * H_SZ + ocol]         = h0;
    out[B_SZ * H_SZ + gbrow * H_SZ + ocol + 1]     = h1;
    out[2 * B_SZ * H_SZ + gbrow * H_SZ + ocol]     = c0;
    out[2 * B_SZ * H_SZ + gbrow * H_SZ + ocol + 1] = c1;
}

extern "C" void kernel_launch(void* const* d_in, const int* in_sizes, int n_in,
                              void* d_out, int out_size, void* d_ws, size_t ws_size,
                              hipStream_t stream) {
    const float* x    = (const float*)d_in[0];
    const float* hx   = (const float*)d_in[1];
    const float* cx   = (const float*)d_in[2];
    const float* W_ih = (const float*)d_in[3];
    const float* W_hh = (const float*)d_in[4];
    const float* b_ih = (const float*)d_in[5];
    const float* b_hh = (const float*)d_in[6];
    float* out = (float*)d_out;

    // ws: [0, 512KB) tagged h double-buffer
    u64t* hbuf = (u64t*)d_ws;

    clear_hbuf_kernel<<<64, 256, 0, stream>>>(hbuf);
    lstm_persistent<<<NWG, NTHR, 0, stream>>>(x, hx, cx, W_ih, W_hh, b_ih, b_hh,
                                              out, hbuf);
}

// Round 20
// 6489.542 us; speedup vs baseline: 1.1936x; 1.0077x over previous
//
#include <hip/hip_runtime.h>
#include <hip/hip_fp16.h>

#define T_STEPS 2048
#define B_SZ 128
#define I_SZ 10
#define H_SZ 512

#define NGRP 8            // batch groups (16 rows each)
#define GWG 8             // wgs per group
#define NWG (NGRP * GWG)  // 64 workgroups
#define BSLICE 16         // batch rows per group
#define WCOL 64           // hidden cols per wg
#define NTHR 512

typedef _Float16 f16x8 __attribute__((ext_vector_type(8)));
typedef float f32x4 __attribute__((ext_vector_type(4)));
typedef float f32x2 __attribute__((ext_vector_type(2)));
typedef unsigned u32x4 __attribute__((ext_vector_type(4)));
typedef unsigned u32x2 __attribute__((ext_vector_type(2)));
typedef unsigned long long u64t;

// Tagged h buffers: [2][NGRP][BSLICE][H/2] u64, u64 = (tag << 32) | 2xfp16.
// MUST be zeroed before every persistent launch (stale tags / 0xAA poison
// would satisfy the tag check).
__global__ void clear_hbuf_kernel(u64t* p) {
    const int i = blockIdx.x * 256 + threadIdx.x;   // 16384 threads
    #pragma unroll
    for (int k = 0; k < 4; ++k)
        __hip_atomic_store(p + i + k * 16384, 0ull,
                           __ATOMIC_RELAXED, __HIP_MEMORY_SCOPE_AGENT);
}

// Persistent LSTM — FINAL (R13 structure, best measured: 6.49 ms).
//
//   8 batch-groups x 8 wgs; wg owns 64 hidden cols (all 4 gates, full K) of
//   its group's 16 batch rows; 8 waves; wf[2][16] fp16 register-resident
//   (128 VGPR, 2 waves/SIMD).
//
//   publish: each thread fire-and-forgets ONE tagged u64 {t+2 | 2xfp16}
//   (relaxed agent-scope atomic = sc0 sc1, coherent at LLC). No drain,
//   no flag array, no release barrier — the store IS the signal.
//   consume: wave0 spins on 8 SENTINEL granules (the u64 written by thread
//   511 of each producer wg; spread across 8 distinct cache lines — the
//   compact shared-line variant REGRESSED, R18) -> spinB -> ONE coalesced
//   sweep (1KB contiguous per instruction) with per-granule tag validation;
//   stale granules re-read exec-masked. Correctness rests on granule tags
//   only, never on sentinels.
//
// Structural floor analysis (R8-R19): per step = publish LLC visibility
// (~0.4us) + detect RTT (~0.5) + 16KB slice read RTT (~0.6) + compute/
// exchange (~0.6) + max-of-8 skew (~1) ~= 3.1us; measured 3.17us/step.
// Register capacity (2MB W_hh fp16 vs 256KB weight-VGPRs per wg) forces
// fan-in >= 8; cross-XCD coherence forces LLC-mediated exchange (sc0-only
// L2 paths deadlock — R6). All cheaper protocol variants tested; this one
// is the floor.
//
// Double-buffer safety (R9/R10/R13 proof): publish at end of step s writes
// tag s+2 into buf[(s+1)&1]; overwriting buf[p] again requires every wg to
// have passed staging(t) of buf[p], enforced by the granule tag chain.
// Intra-8B atomicity: one store per granule; no torn tag/payload.
// LDS hazards: h_stage reads(t) precede B2(t) < spinB(t+1) < staging
// writes(t+1); lds_g writes(t+1) post-B1(t+1) vs reads(t) post-B2(t).
__global__ __launch_bounds__(NTHR, 2) void lstm_persistent(
    const float* __restrict__ x,     // [T,B,I]
    const float* __restrict__ hx,    // [B,H]
    const float* __restrict__ cx,    // [B,H]
    const float* __restrict__ W_ih,  // [4H,I]
    const float* __restrict__ W_hh,  // [4H,H]
    const float* __restrict__ b_ih,  // [4H]
    const float* __restrict__ b_hh,  // [4H]
    float* __restrict__ out,         // [3*B*H] = h, h, c
    u64t* hbuf)                      // [2][NGRP][BSLICE][H/2] tagged
{
    __shared__ _Float16 h_stage[BSLICE][520];   // row stride 1040B
    __shared__ float lds_g[4 * WCOL][17];       // [gate*64+col][row], padded

    const int wg   = blockIdx.x;
    const int g    = wg >> 3;          // batch group 0..7
    const int wgin = wg & 7;           // wg within group 0..7
    const int tid  = threadIdx.x;
    const int wid  = tid >> 6;         // wave 0..7
    const int lane = tid & 63;
    const int fr_col = lane & 15;
    const int fr_kg  = lane >> 4;      // 0..3

    // ---- this wave's two gate-column fragments (wg covers 256 gate-cols)
    int gcL[2], wr[2];
    #pragma unroll
    for (int f = 0; f < 2; ++f) {
        gcL[f] = wid * 32 + f * 16 + fr_col;              // 0..255
        wr[f]  = (gcL[f] >> 6) * H_SZ + wgin * WCOL + (gcL[f] & 63);
    }

    // ---- W_hh B-fragments: 2 frags x 16 K-chunks, fp16 register-resident
    f16x8 wf[2][16];
    #pragma unroll
    for (int f = 0; f < 2; ++f)
        #pragma unroll
        for (int c = 0; c < 16; ++c) {
            const float* p = W_hh + (size_t)wr[f] * H_SZ + c * 32 + fr_kg * 8;
            f16x8 w;
            #pragma unroll
            for (int e = 0; e < 8; ++e) w[e] = (_Float16)p[e];
            wf[f][c] = w;
        }

    // ---- W_ih rows + combined bias
    float wih[2][I_SZ], bias[2];
    #pragma unroll
    for (int f = 0; f < 2; ++f) {
        #pragma unroll
        for (int i = 0; i < I_SZ; ++i) wih[f][i] = W_ih[wr[f] * I_SZ + i];
        bias[f] = b_ih[wr[f]] + b_hh[wr[f]];
    }

    // ---- owned cells: 2 adjacent per thread (16 rows x 64 cols per wg)
    const int orow  = tid >> 5;                    // 0..15
    const int ocol  = wgin * WCOL + 2 * (tid & 31);
    const int gbrow = g * BSLICE + orow;
    const size_t my_q = (size_t)orow * 256 + (ocol >> 1);   // u64 idx in slice

    float c0 = cx[gbrow * H_SZ + ocol];
    float c1 = cx[gbrow * H_SZ + ocol + 1];
    float h0 = hx[gbrow * H_SZ + ocol];
    float h1 = hx[gbrow * H_SZ + ocol + 1];

    // ---- staging geometry (coalesced): piece j of this lane
    int   st_row[4], st_p[4];
    bool  st_own[4];
    #pragma unroll
    for (int j = 0; j < 4; ++j) {
        const int q = wid * 512 + j * 128 + lane * 2;
        st_row[j] = q >> 8;
        st_p[j]   = q & 255;
        st_own[j] = ((st_p[j] >> 5) == wgin);
    }

    // ---- sentinel for producer wg p = granule (row 15, last colpair of p)
    //      written by p's thread 511: idx = 15*256 + p*32 + 31
    const int sent_idx = 15 * 256 + (lane & 7) * 32 + 31;

    // ---- publish h(0) with tag 1 into buffer 0 + own-tile LDS write
    {
        u64t* hb0 = hbuf + (size_t)g * (BSLICE * 256);
        union { _Float16 hp[2]; unsigned u; } pk;
        pk.hp[0] = (_Float16)h0; pk.hp[1] = (_Float16)h1;
        __hip_atomic_store(hb0 + my_q, ((u64t)1u << 32) | pk.u,
                           __ATOMIC_RELAXED, __HIP_MEMORY_SCOPE_AGENT);
        *(unsigned*)&h_stage[orow][ocol] = pk.u;
    }

    #pragma unroll 1
    for (int t = 0; t < T_STEPS; ++t) {
        // -- x_t @ W_ih^T + bias (h-independent; overlaps sentinel landing)
        f32x4 acc[2];
        #pragma unroll
        for (int r = 0; r < 4; ++r) {
            const int grow = g * BSLICE + fr_kg * 4 + r;
            const f32x2* xp = (const f32x2*)(x + ((size_t)t * B_SZ + grow) * I_SZ);
            const f32x2 a0 = xp[0], a1 = xp[1], a2 = xp[2], a3 = xp[3], a4 = xp[4];
            #pragma unroll
            for (int f = 0; f < 2; ++f) {
                float s = bias[f];
                s += a0.x*wih[f][0] + a0.y*wih[f][1] + a1.x*wih[f][2] + a1.y*wih[f][3]
                   + a2.x*wih[f][4] + a2.y*wih[f][5] + a3.x*wih[f][6] + a3.y*wih[f][7]
                   + a4.x*wih[f][8] + a4.y*wih[f][9];
                acc[f][r] = s;
            }
        }

        const u64t* hb = hbuf + ((size_t)(t & 1) * NGRP + g) * (BSLICE * 256);
        const unsigned tgt = (unsigned)(t + 1);

        // -- sentinel spin: wave0 only (8 granules on 8 distinct lines)
        if (wid == 0) {
            const u64t* sp = hb + sent_idx;
            for (;;) {
                u64t sv = __hip_atomic_load(sp, __ATOMIC_RELAXED,
                                            __HIP_MEMORY_SCOPE_AGENT);
                if (__all((unsigned)(sv >> 32) >= tgt)) break;
                __builtin_amdgcn_s_sleep(1);
            }
        }
        __syncthreads();   // spinB: sentinels fresh; also fences h_stage WAR

        // -- ONE coalesced tagged sweep (validate tags; stale granules
        //    re-read exec-masked; own pieces skip — already in LDS)
        {
            const char* sp = (const char*)hb + wid * 4096 + lane * 16;
            u32x4 q0, q1, q2, q3;
            bool done = false;
            for (;;) {
                if (!done) {
                    asm volatile(
                        "global_load_dwordx4 %0, %4, off sc0 sc1\n\t"
                        "global_load_dwordx4 %1, %4, off offset:1024 sc0 sc1\n\t"
                        "global_load_dwordx4 %2, %4, off offset:2048 sc0 sc1\n\t"
                        "global_load_dwordx4 %3, %4, off offset:3072 sc0 sc1\n\t"
                        "s_waitcnt vmcnt(0)"
                        : "=&v"(q0), "=&v"(q1), "=&v"(q2), "=&v"(q3)
                        : "v"(sp) : "memory");
                    done = (st_own[0] || (q0.y >= tgt && q0.w >= tgt)) &&
                           (st_own[1] || (q1.y >= tgt && q1.w >= tgt)) &&
                           (st_own[2] || (q2.y >= tgt && q2.w >= tgt)) &&
                           (st_own[3] || (q3.y >= tgt && q3.w >= tgt));
                }
                if (__all(done)) break;
                __builtin_amdgcn_s_sleep(1);
            }
            if (!st_own[0]) *(u32x2*)&h_stage[st_row[0]][st_p[0] * 2] = (u32x2){q0.x, q0.z};
            if (!st_own[1]) *(u32x2*)&h_stage[st_row[1]][st_p[1] * 2] = (u32x2){q1.x, q1.z};
            if (!st_own[2]) *(u32x2*)&h_stage[st_row[2]][st_p[2] * 2] = (u32x2){q2.x, q2.z};
            if (!st_own[3]) *(u32x2*)&h_stage[st_row[3]][st_p[3] * 2] = (u32x2){q3.x, q3.z};
        }
        __syncthreads();   // B1: staging visible

        // -- 16 K-chunks: ds_read A-frag, 2 MFMAs each
        #pragma unroll
        for (int c = 0; c < 16; ++c) {
            const f16x8 a = *(const f16x8*)&h_stage[fr_col][c * 32 + fr_kg * 8];
            acc[0] = __builtin_amdgcn_mfma_f32_16x16x32_f16(a, wf[0][c], acc[0], 0, 0, 0);
            acc[1] = __builtin_amdgcn_mfma_f32_16x16x32_f16(a, wf[1][c], acc[1], 0, 0, 0);
        }

        // -- gate pre-activations -> LDS
        #pragma unroll
        for (int f = 0; f < 2; ++f)
            #pragma unroll
            for (int r = 0; r < 4; ++r)
                lds_g[gcL[f]][fr_kg * 4 + r] = acc[f][r];
        __syncthreads();   // B2: gates visible; fences all h_stage reads

        // -- c/h update; fire-and-forget tagged publish + own-tile shortcut
        {
            const int cl = 2 * (tid & 31);
            const float i0 = lds_g[0 * WCOL + cl][orow],     f0 = lds_g[1 * WCOL + cl][orow];
            const float g0 = lds_g[2 * WCOL + cl][orow],     o0 = lds_g[3 * WCOL + cl][orow];
            const float i1 = lds_g[0 * WCOL + cl + 1][orow], f1 = lds_g[1 * WCOL + cl + 1][orow];
            const float g1 = lds_g[2 * WCOL + cl + 1][orow], o1 = lds_g[3 * WCOL + cl + 1][orow];

            const float ig0 = 1.f / (1.f + __expf(-i0));
            const float fg0 = 1.f / (1.f + __expf(-f0));
            const float eg0 = __expf(-2.f * g0);
            const float tg0 = (1.f - eg0) / (1.f + eg0);
            const float og0 = 1.f / (1.f + __expf(-o0));
            const float ig1 = 1.f / (1.f + __expf(-i1));
            const float fg1 = 1.f / (1.f + __expf(-f1));
            const float eg1 = __expf(-2.f * g1);
            const float tg1 = (1.f - eg1) / (1.f + eg1);
            const float og1 = 1.f / (1.f + __expf(-o1));

            c0 = fg0 * c0 + ig0 * tg0;
            c1 = fg1 * c1 + ig1 * tg1;
            const float e0 = __expf(-2.f * c0), e1 = __expf(-2.f * c1);
            h0 = og0 * (1.f - e0) / (1.f + e0);
            h1 = og1 * (1.f - e1) / (1.f + e1);

            if (t < T_STEPS - 1) {
                u64t* hbn = hbuf + ((size_t)((t + 1) & 1) * NGRP + g) * (BSLICE * 256);
                union { _Float16 hp[2]; unsigned u; } pk;
                pk.hp[0] = (_Float16)h0; pk.hp[1] = (_Float16)h1;
                __hip_atomic_store(hbn + my_q,
                                   ((u64t)(unsigned)(t + 2) << 32) | pk.u,
                                   __ATOMIC_RELAXED, __HIP_MEMORY_SCOPE_AGENT);
                *(unsigned*)&h_stage[orow][ocol] = pk.u;   // own-tile shortcut
            }
        }
    }

    // ---- outputs: (h, h, c), each [B,H] f32
    out[gbrow * H_SZ + ocol]                       = h0;
    out[gbrow * H_SZ + ocol + 1]                   = h1;
    out[B_SZ * H_SZ + gbrow * H_SZ + ocol]         = h0;
    out[B_SZ * H_SZ + gbrow * H_SZ + ocol + 1]     = h1;
    out[2 * B_SZ * H_SZ + gbrow * H_SZ + ocol]     = c0;
    out[2 * B_SZ * H_SZ + gbrow * H_SZ + ocol + 1] = c1;
}

extern "C" void kernel_launch(void* const* d_in, const int* in_sizes, int n_in,
                              void* d_out, int out_size, void* d_ws, size_t ws_size,
                              hipStream_t stream) {
    const float* x    = (const float*)d_in[0];
    const float* hx   = (const float*)d_in[1];
    const float* cx   = (const float*)d_in[2];
    const float* W_ih = (const float*)d_in[3];
    const float* W_hh = (const float*)d_in[4];
    const float* b_ih = (const float*)d_in[5];
    const float* b_hh = (const float*)d_in[6];
    float* out = (float*)d_out;

    // ws: [0, 512KB) tagged h double-buffer
    u64t* hbuf = (u64t*)d_ws;

    clear_hbuf_kernel<<<64, 256, 0, stream>>>(hbuf);
    lstm_persistent<<<NWG, NTHR, 0, stream>>>(x, hx, cx, W_ih, W_hh, b_ih, b_hh,
                                              out, hbuf);
}